// Round 6
// baseline (603.204 us; speedup 1.0000x reference)
//
#include <hip/hip_runtime.h>

typedef unsigned long long u64;
typedef unsigned int u32;

#define MAXN 8704            // 8700 rounded to 64
#define MAXNW 144
#define CHUNK 512            // j-chunk for rank kernel
#define NFAR 34              // far-worker blocks (nw=136 = 34*4)

__device__ inline u64 shfl_xor_u64(u64 v, int m) {
    u32 lo = (u32)v, hi = (u32)(v >> 32);
    lo = (u32)__shfl_xor((int)lo, m, 64);
    hi = (u32)__shfl_xor((int)hi, m, 64);
    return ((u64)hi << 32) | lo;
}

// ---------------- K0: merge + clip + cxcywh->xyxy + sort key + ws init ------
__global__ void prep_kernel(const float* __restrict__ yb, const float* __restrict__ yc,
                            const float* __restrict__ db, const float* __restrict__ dc,
                            int n1, int n,
                            float4* __restrict__ xyxy, float* __restrict__ conf,
                            u32* __restrict__ key, int* __restrict__ rank,
                            u64* __restrict__ remv_g, u32* __restrict__ kflag,
                            u32* __restrict__ dflag) {
    int i = blockIdx.x * 256 + threadIdx.x;
    if (i < MAXN) rank[i] = 0;
    if (i < MAXNW) { remv_g[i] = 0; kflag[i] = 0; dflag[i] = 0; }
    if (i >= n) return;
    float cx, cy, w, h, c;
    if (i < n1) {
        const float* b = yb + (size_t)i * 4;
        cx = b[0]; cy = b[1]; w = b[2]; h = b[3]; c = yc[i];
    } else {
        const float* b = db + (size_t)(i - n1) * 4;
        cx = b[0]; cy = b[1]; w = b[2]; h = b[3]; c = dc[i - n1];
    }
    c = fminf(fmaxf(c, 0.0f), 1.0f);
    float hw = w * 0.5f, hh = h * 0.5f;
    xyxy[i] = make_float4(cx - hw, cy - hh, cx + hw, cy + hh);
    conf[i] = c;
    key[i]  = __float_as_uint(c);
}

// ---------------- K1: O(N^2) stable rank ------------------------------------
__global__ void rank_kernel(const u32* __restrict__ key, int n, int* __restrict__ rank) {
    __shared__ __align__(16) u32 sk[CHUNK];
    int t = threadIdx.x;
    int jbase = blockIdx.y * CHUNK;
    for (int s = t; s < CHUNK; s += 256) {
        int j = jbase + s;
        sk[s] = (j < n) ? key[j] : 0u;
    }
    __syncthreads();
    int i = blockIdx.x * 256 + t;
    if (i >= n) return;
    u32 ki = key[i];
    int cnt = 0;
    const uint4* sk4 = (const uint4*)sk;
    for (int s = 0; s < CHUNK / 4; ++s) {
        uint4 k = sk4[s];
        int j = jbase + s * 4;
        cnt += (k.x > ki) || (k.x == ki && (j + 0) < i);
        cnt += (k.y > ki) || (k.y == ki && (j + 1) < i);
        cnt += (k.z > ki) || (k.z == ki && (j + 2) < i);
        cnt += (k.w > ki) || (k.w == ki && (j + 3) < i);
    }
    if (cnt) atomicAdd(&rank[i], cnt);
}

// ---------------- K2: scatter into sorted order -----------------------------
__global__ void scatter_kernel(const float4* __restrict__ xyxy, const float* __restrict__ conf,
                               const int* __restrict__ rank, int n,
                               float4* __restrict__ sbox, float* __restrict__ sconf) {
    int i = blockIdx.x * 256 + threadIdx.x;
    if (i >= n) return;
    int r = rank[i];
    sbox[r]  = xyxy[i];
    sconf[r] = conf[i];
}

// ---------------- K3: suppression bit-matrix + transposed band --------------
// sup[i][bj] bit k set <=> j = 64*bj+k, j > i, iou(i,j) > 0.5
// bandT2[bi][row][d] = sup word (row of chunk bi, word bi+d), d=0..3 -- lets
// the solver read its diag+near band with 2 coalesced 16B loads per lane.
__global__ void iou_kernel(const float4* __restrict__ sbox, int n, int nw,
                           u64* __restrict__ sup, u64* __restrict__ bandT2) {
    int bi = blockIdx.y, bj = blockIdx.x;
    if (bj < bi) return;
    __shared__ float4 cb[64];
    int t  = threadIdx.x;
    int j0 = bj * 64;
    int jt = j0 + t;
    cb[t] = (jt < n) ? sbox[jt] : make_float4(0, 0, 0, 0);
    __syncthreads();
    int i = bi * 64 + t;
    if (i >= n) return;
    float4 a = sbox[i];
    float areaA = (a.z - a.x) * (a.w - a.y);
    u64 word = 0;
    int kmax = min(64, n - j0);
    for (int k = 0; k < kmax; ++k) {
        int j = j0 + k;
        float4 b = cb[k];
        float iw = fmaxf(fminf(a.z, b.z) - fmaxf(a.x, b.x), 0.0f);
        float ih = fmaxf(fminf(a.w, b.w) - fmaxf(a.y, b.y), 0.0f);
        float inter = iw * ih;
        float areaB = (b.z - b.x) * (b.w - b.y);
        float uni = areaA + areaB - inter;
        float iou = inter / fmaxf(uni, 1e-9f);
        if (j > i && iou > 0.5f) word |= (1ULL << k);
    }
    sup[(size_t)i * nw + bj] = word;
    int d = bj - bi;
    if (d < 4) bandT2[((size_t)bi * 64 + t) * 4 + d] = word;
}

// ---------------- K4: producer-consumer forward-substitution NMS ------------
// Block 0 (1 wave): serial ctz-solve chain. Per chunk p: resolve far word
// (prefetch-and-verify vs done-flag frontier), solve diag, publish keep-word
// (release), near-update words p+1..p+3 via shfl-trees into LDS, issue next
// band / far / flag loads (all >= 1 phase of slack -> no exposed latency).
// Blocks 1..NFAR (512 thr): per assigned chunk q: spin-acquire keep-word,
// write output rows, stream far columns (words >= q+4, coalesced, spread
// over 34 CUs), atomicOr into remv_g, fence, release done-flag.
// Coverage of word w: diag (chunk w) + near (chunks w-3..w-1, LDS) +
// far (chunks q <= w-4, remv_g). Exact greedy NMS.
__device__ __forceinline__ void solver_phase(
    int p, int n, int nw, int t,
    const ulonglong2* __restrict__ bt,
    u64* s_remv,
    u64* kw_g, u32* kflag, u32* dflag, u64* remv_g,
    ulonglong2& BU0, ulonglong2& BU1,     // band[p]   (consume)
    ulonglong2& BI0, ulonglong2& BI1,     // band[p+2] (issue)
    u64& fv_c, int& fvok_c,               // remv_g[p]   (consume)
    u64& fv_n, int& fvok_n,               // remv_g[p+1] (issue)
    u32& FLv, int& FLbase, int& frontier)
{
    if (p >= nw) return;
    // [1] resolve far word for p
    u64 farv;
    if (fvok_c) {
        farv = fv_c;
    } else {
        while (frontier < p - 3) {   // rare fallback
            u32 f2 = __hip_atomic_load(&dflag[min(frontier + t, nw - 1)],
                                       __ATOMIC_RELAXED, __HIP_MEMORY_SCOPE_AGENT);
            u64 bm = __ballot((frontier + t >= nw) || f2 != 0);
            int adv = (~bm) ? (int)__builtin_ctzll(~bm) : 64;
            if (!adv) __builtin_amdgcn_s_sleep(2);
            frontier = min(frontier + adv, nw);
        }
        farv = __hip_atomic_load(&remv_g[p], __ATOMIC_RELAXED, __HIP_MEMORY_SCOPE_AGENT);
    }
    // [2] solve chunk p (ctz-skip chain, diag slices in lane regs)
    int rem = n - (p << 6);
    u64 vm = (rem >= 64) ? ~0ull : (rem <= 0 ? 0ull : ((1ull << rem) - 1ull));
    u64 cand = ~(s_remv[p] | farv) & vm;
    u64 kw = 0;
    u32 dlo = (u32)BU0.x, dhi = (u32)(BU0.x >> 32);
    while (cand) {
        int k1 = __builtin_amdgcn_readfirstlane((int)__builtin_ctzll(cand));
        u64 s1 = (((u64)(u32)__builtin_amdgcn_readlane((int)dhi, k1)) << 32)
               |  ((u64)(u32)__builtin_amdgcn_readlane((int)dlo, k1));
        u64 c1 = cand & ~(1ull << k1);
        kw |= 1ull << k1;
        if (c1) {   // speculative second candidate (suppression is sparse)
            int k2 = __builtin_amdgcn_readfirstlane((int)__builtin_ctzll(c1));
            u64 s2 = (((u64)(u32)__builtin_amdgcn_readlane((int)dhi, k2)) << 32)
                   |  ((u64)(u32)__builtin_amdgcn_readlane((int)dlo, k2));
            if (!((s1 >> k2) & 1ull)) {
                kw |= 1ull << k2;
                cand = c1 & ~(1ull << k2) & ~(s1 | s2);
            } else {
                cand = c1 & ~s1;
            }
        } else cand = 0;
    }
    // [3] publish (release: outstanding loads are all >=1 phase old -> landed)
    if (t == 0) {
        kw_g[p] = kw;
        __hip_atomic_store(&kflag[p], 1u, __ATOMIC_RELEASE, __HIP_MEMORY_SCOPE_AGENT);
    }
    // [4] near-update words p+1..p+3 (shfl OR-trees)
    u64 mm = ((kw >> t) & 1ull) ? ~0ull : 0ull;
    u64 r1 = BU0.y & mm, r2 = BU1.x & mm, r3 = BU1.y & mm;
    #pragma unroll
    for (int m = 1; m < 64; m <<= 1) {
        r1 |= shfl_xor_u64(r1, m);
        r2 |= shfl_xor_u64(r2, m);
        r3 |= shfl_xor_u64(r3, m);
    }
    if (t == 0) {
        if (p + 1 < nw) s_remv[p + 1] |= r1;
        if (p + 2 < nw) s_remv[p + 2] |= r2;
        if (p + 3 < nw) s_remv[p + 3] |= r3;
    }
    // [5] frontier advance from flags loaded last phase
    {
        u64 bm = __ballot((FLbase + t >= nw) || FLv != 0);
        int adv = (~bm) ? (int)__builtin_ctzll(~bm) : 64;
        frontier = max(frontier, min(FLbase + adv, nw));
    }
    // [6] prefetch far word for p+1 (valid iff all chunks <= p-3 done at issue)
    fvok_n = (frontier >= p - 2);
    fv_n = __hip_atomic_load(&remv_g[min(p + 1, nw - 1)],
                             __ATOMIC_RELAXED, __HIP_MEMORY_SCOPE_AGENT);
    // [7] band issue for p+2 (coalesced 2x16B per lane)
    {
        int cc = min(p + 2, nw - 1);
        int bidx = (cc * 64 + t) * 2;
        BI0 = bt[bidx]; BI1 = bt[bidx + 1];
    }
    // [8] flag loads for next phase's advance
    FLbase = frontier;
    FLv = __hip_atomic_load(&dflag[min(frontier + t, nw - 1)],
                            __ATOMIC_RELAXED, __HIP_MEMORY_SCOPE_AGENT);
}

__global__ __launch_bounds__(512) void nms_scan(const u64* __restrict__ sup,
                                                const u64* __restrict__ bandT2,
                                                const float4* __restrict__ sbox,
                                                const float* __restrict__ sconf,
                                                int n, int nw,
                                                u64* __restrict__ kw_g,
                                                u64* __restrict__ remv_g,
                                                u32* __restrict__ kflag,
                                                u32* __restrict__ dflag,
                                                float* __restrict__ out) {
    __shared__ u64 s_remv[MAXNW];
    __shared__ u32 s_klist[64];
    __shared__ int s_kcn;

    int t = threadIdx.x;

    if (blockIdx.x == 0) {
        // ================= solver: single wave =================
        if (t >= 64) return;
        for (int i = t; i < MAXNW; i += 64) s_remv[i] = 0;
        const ulonglong2* bt = (const ulonglong2*)bandT2;

        ulonglong2 A0, A1, B0, B1, C0, C1;
        {   // prologue: bands for chunks 0,1
            int i0 = (0 * 64 + t) * 2, i1 = (1 * 64 + t) * 2;
            A0 = bt[i0]; A1 = bt[i0 + 1];
            B0 = bt[i1]; B1 = bt[i1 + 1];
            C0 = make_ulonglong2(0, 0); C1 = C0;
        }
        u64 fv_c = __hip_atomic_load(&remv_g[0], __ATOMIC_RELAXED, __HIP_MEMORY_SCOPE_AGENT);
        int fvok_c = 1;           // words 0..3 have no far contributors
        u64 fv_n = 0; int fvok_n = 0;
        int frontier = 0, FLbase = 0;
        u32 FLv = __hip_atomic_load(&dflag[min(t, nw - 1)],
                                    __ATOMIC_RELAXED, __HIP_MEMORY_SCOPE_AGENT);

        for (int pb = 0; pb < MAXNW; pb += 3) {
            solver_phase(pb + 0, n, nw, t, bt, s_remv, kw_g, kflag, dflag, remv_g,
                         A0, A1, C0, C1, fv_c, fvok_c, fv_n, fvok_n, FLv, FLbase, frontier);
            fv_c = fv_n; fvok_c = fvok_n;
            solver_phase(pb + 1, n, nw, t, bt, s_remv, kw_g, kflag, dflag, remv_g,
                         B0, B1, A0, A1, fv_c, fvok_c, fv_n, fvok_n, FLv, FLbase, frontier);
            fv_c = fv_n; fvok_c = fvok_n;
            solver_phase(pb + 2, n, nw, t, bt, s_remv, kw_g, kflag, dflag, remv_g,
                         C0, C1, B0, B1, fv_c, fvok_c, fv_n, fvok_n, FLv, FLbase, frontier);
            fv_c = fv_n; fvok_c = fvok_n;
            if (pb + 3 >= nw) break;
        }
        return;
    }

    // ================= far workers: blocks 1..NFAR =================
    int b = blockIdx.x - 1;
    for (int k = 0; k < 4; ++k) {
        int q = b + k * NFAR;
        if (q >= nw) break;
        // wait for keep-word of chunk q
        while (__hip_atomic_load(&kflag[q], __ATOMIC_ACQUIRE, __HIP_MEMORY_SCOPE_AGENT) == 0)
            __builtin_amdgcn_s_sleep(8);
        u64 kw = kw_g[q];
        // masked output rows of chunk q (folded-in out kernel)
        if (t < 320) {
            int rr = t / 5, c5 = t - rr * 5;
            int r = (q << 6) + rr;
            if (r < n) {
                float keep = ((kw >> rr) & 1ull) ? 1.0f : 0.0f;
                float v = (c5 < 4) ? ((const float*)sbox)[(size_t)r * 4 + c5] : sconf[r];
                out[(size_t)r * 5 + c5] = v * keep;
            }
        }
        // kept-row list
        if (t < 64 && ((kw >> t) & 1ull))
            s_klist[__popcll(kw & ((1ull << t) - 1ull))] = (u32)t;
        if (t == 0) s_kcn = __popcll(kw);
        __syncthreads();
        int kc = s_kcn;
        if (kc > 0 && q + 4 < nw) {
            int base = t & 3;                 // row subset
            int wsl  = t >> 2;                // word slot 0..127
            int cnt = (kc > base) ? ((kc - base + 3) >> 2) : 0;
            u32 kr[16];
            #pragma unroll
            for (int j = 0; j < 16; ++j) kr[j] = s_klist[min(base + 4 * j, kc - 1)];
            for (int w = q + 4 + wsl; w < nw; w += 128) {
                u64 acc = 0;
                #pragma unroll 4
                for (int j = 0; j < cnt; ++j)
                    acc |= sup[(size_t)((q << 6) + kr[j]) * nw + w];
                if (acc) atomicOr((unsigned long long*)&remv_g[w], (unsigned long long)acc);
            }
        }
        __threadfence();
        __syncthreads();
        if (t == 0)
            __hip_atomic_store(&dflag[q], 1u, __ATOMIC_RELEASE, __HIP_MEMORY_SCOPE_AGENT);
        __syncthreads();
    }
}

// ---------------- launch -----------------------------------------------------
extern "C" void kernel_launch(void* const* d_in, const int* in_sizes, int n_in,
                              void* d_out, int out_size, void* d_ws, size_t ws_size,
                              hipStream_t stream) {
    const float* yb = (const float*)d_in[0];
    const float* yc = (const float*)d_in[1];
    const float* db = (const float*)d_in[2];
    const float* dc = (const float*)d_in[3];
    int n1 = in_sizes[1];
    int n2 = in_sizes[3];
    int n  = n1 + n2;                          // 8700
    int nw = (n + 63) / 64;                    // 136

    char* w = (char*)d_ws;
    u64*    sup    = (u64*)w;                                  // MAXN*nw*8 ~ 9.47 MB
    u64*    bandT2 = (u64*)(w + (size_t)MAXN * nw * 8);        // MAXNW*64*4 u64
    float4* xyxy   = (float4*)(bandT2 + (size_t)MAXNW * 64 * 4);
    float4* sbox   = xyxy + MAXN;
    float*  conf   = (float*)(sbox + MAXN);
    float*  sconf  = conf + MAXN;
    u32*    key    = (u32*)(sconf + MAXN);
    int*    rank   = (int*)(key + MAXN);
    u64*    kw_g   = (u64*)(rank + MAXN);                      // MAXNW
    u64*    remv_g = kw_g + MAXNW;                             // MAXNW
    u32*    kflag  = (u32*)(remv_g + MAXNW);                   // MAXNW
    u32*    dflag  = kflag + MAXNW;                            // MAXNW

    int nb = (n + 255) / 256;                                  // 34
    prep_kernel<<<nb, 256, 0, stream>>>(yb, yc, db, dc, n1, n, xyxy, conf, key, rank,
                                        remv_g, kflag, dflag);

    dim3 g1(nb, (n + CHUNK - 1) / CHUNK);                      // 34 x 17
    rank_kernel<<<g1, 256, 0, stream>>>(key, n, rank);

    scatter_kernel<<<nb, 256, 0, stream>>>(xyxy, conf, rank, n, sbox, sconf);

    dim3 g3(nw, nw);                                           // 136 x 136 (upper tri active)
    iou_kernel<<<g3, 64, 0, stream>>>(sbox, n, nw, sup, bandT2);

    nms_scan<<<1 + NFAR, 512, 0, stream>>>(sup, bandT2, sbox, sconf, n, nw,
                                           kw_g, remv_g, kflag, dflag, (float*)d_out);
}

// Round 7
// 591.287 us; speedup vs baseline: 1.0202x; 1.0202x over previous
//
#include <hip/hip_runtime.h>

typedef unsigned long long u64;
typedef unsigned int u32;

#define MAXN 8704            // 8700 rounded to 64
#define MAXNW 144
#define CHUNK 512            // j-chunk for rank kernel
#define EC 4096              // edge-word slots per source chunk (~50x headroom)
#define EPF 5                // edge regs/thread: 448*5 = 2240 slots fast path

__device__ inline u64 shfl_xor_u64(u64 v, int m) {
    u32 lo = (u32)v, hi = (u32)(v >> 32);
    lo = (u32)__shfl_xor((int)lo, m, 64);
    hi = (u32)__shfl_xor((int)hi, m, 64);
    return ((u64)hi << 32) | lo;
}

// lgkm-only phase barrier: LDS visible across it, global loads STAY IN FLIGHT
__device__ __forceinline__ void lgkm_barrier() {
    __builtin_amdgcn_sched_barrier(0);
    asm volatile("s_waitcnt lgkmcnt(0)" ::: "memory");
    __builtin_amdgcn_s_barrier();
    __builtin_amdgcn_sched_barrier(0);
}

// ---------------- K0: merge + clip + cxcywh->xyxy + sort key + ws init ------
__global__ void prep_kernel(const float* __restrict__ yb, const float* __restrict__ yc,
                            const float* __restrict__ db, const float* __restrict__ dc,
                            int n1, int n,
                            float4* __restrict__ xyxy, float* __restrict__ conf,
                            u32* __restrict__ key, int* __restrict__ rank,
                            u64* __restrict__ db2, int* __restrict__ ecnt) {
    int i = blockIdx.x * 256 + threadIdx.x;
    if (i < MAXN) { rank[i] = 0; db2[2 * i] = 0; db2[2 * i + 1] = 0; }
    if (i < MAXNW) ecnt[i] = 0;
    if (i >= n) return;
    float cx, cy, w, h, c;
    if (i < n1) {
        const float* b = yb + (size_t)i * 4;
        cx = b[0]; cy = b[1]; w = b[2]; h = b[3]; c = yc[i];
    } else {
        const float* b = db + (size_t)(i - n1) * 4;
        cx = b[0]; cy = b[1]; w = b[2]; h = b[3]; c = dc[i - n1];
    }
    c = fminf(fmaxf(c, 0.0f), 1.0f);
    float hw = w * 0.5f, hh = h * 0.5f;
    xyxy[i] = make_float4(cx - hw, cy - hh, cx + hw, cy + hh);
    conf[i] = c;
    key[i]  = __float_as_uint(c);
}

// ---------------- K1: O(N^2) stable rank ------------------------------------
__global__ void rank_kernel(const u32* __restrict__ key, int n, int* __restrict__ rank) {
    __shared__ __align__(16) u32 sk[CHUNK];
    int t = threadIdx.x;
    int jbase = blockIdx.y * CHUNK;
    for (int s = t; s < CHUNK; s += 256) {
        int j = jbase + s;
        sk[s] = (j < n) ? key[j] : 0u;
    }
    __syncthreads();
    int i = blockIdx.x * 256 + t;
    if (i >= n) return;
    u32 ki = key[i];
    int cnt = 0;
    const uint4* sk4 = (const uint4*)sk;
    for (int s = 0; s < CHUNK / 4; ++s) {
        uint4 k = sk4[s];
        int j = jbase + s * 4;
        cnt += (k.x > ki) || (k.x == ki && (j + 0) < i);
        cnt += (k.y > ki) || (k.y == ki && (j + 1) < i);
        cnt += (k.z > ki) || (k.z == ki && (j + 2) < i);
        cnt += (k.w > ki) || (k.w == ki && (j + 3) < i);
    }
    if (cnt) atomicAdd(&rank[i], cnt);
}

// ---------------- K2: scatter into sorted order -----------------------------
__global__ void scatter_kernel(const float4* __restrict__ xyxy, const float* __restrict__ conf,
                               const int* __restrict__ rank, int n,
                               float4* __restrict__ sbox, float* __restrict__ sconf) {
    int i = blockIdx.x * 256 + threadIdx.x;
    if (i >= n) return;
    int r = rank[i];
    sbox[r]  = xyxy[i];
    sconf[r] = conf[i];
}

// ---------------- K3: SPARSE suppression structure ---------------------------
// For row i (chunk bi), word bj (>= bi):
//   d=0 -> db2[2*i]   (diagonal 64x64 block)
//   d=1 -> db2[2*i+1] (near band, handled by solver's shfl-tree)
//   d>=2 & word!=0 -> edge-word {einfo=(row<<8)|bj, emask=word} bucketed by bi.
// The bitmap is ~99.95% zero, so edge-words total a few thousand.
__global__ void iou_kernel(const float4* __restrict__ sbox, int n, int nw,
                           u64* __restrict__ db2,
                           u32* __restrict__ einfo, u64* __restrict__ emask,
                           int* __restrict__ ecnt) {
    int bi = blockIdx.y, bj = blockIdx.x;
    if (bj < bi) return;
    __shared__ float4 cb[64];
    int t  = threadIdx.x;
    int j0 = bj * 64;
    int jt = j0 + t;
    cb[t] = (jt < n) ? sbox[jt] : make_float4(0, 0, 0, 0);
    __syncthreads();
    int i = bi * 64 + t;
    if (i >= n) return;
    float4 a = sbox[i];
    float areaA = (a.z - a.x) * (a.w - a.y);
    u64 word = 0;
    int kmax = min(64, n - j0);
    for (int k = 0; k < kmax; ++k) {
        int j = j0 + k;
        float4 b = cb[k];
        float iw = fmaxf(fminf(a.z, b.z) - fmaxf(a.x, b.x), 0.0f);
        float ih = fmaxf(fminf(a.w, b.w) - fmaxf(a.y, b.y), 0.0f);
        float inter = iw * ih;
        float areaB = (b.z - b.x) * (b.w - b.y);
        float uni = areaA + areaB - inter;
        float iou = inter / fmaxf(uni, 1e-9f);
        if (j > i && iou > 0.5f) word |= (1ULL << k);
    }
    int d = bj - bi;
    if (d == 0)      db2[2 * (size_t)i]     = word;
    else if (d == 1) db2[2 * (size_t)i + 1] = word;
    else if (word) {
        int slot = atomicAdd(&ecnt[bi], 1);
        if (slot < EC) {
            einfo[(size_t)bi * EC + slot] = ((u32)t << 8) | (u32)bj;
            emask[(size_t)bi * EC + slot] = word;
        }
    }
}

// ---------------- K4: single-block sparse forward-substitution NMS ----------
// One 512-thread block. Dependency loop is LDS-ONLY; all global reads are
// feed-forward prefetches with >= 2-phase slack. Per phase p:
//   wave0: ctz-solve diag word p (diag in regs, prefetched 2 ahead); write
//          keep-word to LDS; shfl-tree near word p+1 from band regs; issue
//          db2 regs for p+2.
//   waves 1-7: APPLY chunk p-1's edge-words (gated by its keep-word; targets
//          >= p+1, never the word being solved); slow path if cnt > 2240;
//          ISSUE chunk p+1's edge-words into regs (static addresses).
// One lgkm-only barrier per phase. Coverage of word w: diag (phase w) +
// band1 (phase w-1 tree) + edges from chunks q<=w-2 (applied phase q+1<=w-1).
// Exact greedy NMS.
template<int PW>
__device__ __forceinline__ void phase_step(
    int p, int n, int nw, int t, int tf,
    const ulonglong2* __restrict__ db2v,
    const u32* __restrict__ einfo, const u64* __restrict__ emask,
    u64* s_remv, u64* s_kws, int* s_cnt,
    ulonglong2& BU, ulonglong2& BI,
    u32 (&EI)[EPF], u64 (&EM)[EPF])
{
    if (t < 64) {
        // ---- solve chunk p (wave 0; diag slices in lane regs) ----
        int rem = n - (p << 6);
        u64 vm = (rem >= 64) ? ~0ull : (rem <= 0 ? 0ull : ((1ull << rem) - 1ull));
        u64 cand = (p < nw) ? (~s_remv[p] & vm) : 0ull;
        u64 kw = 0;
        u32 dlo = (u32)BU.x, dhi = (u32)(BU.x >> 32);
        while (cand) {
            int k1 = __builtin_amdgcn_readfirstlane((int)__builtin_ctzll(cand));
            u64 s1 = (((u64)(u32)__builtin_amdgcn_readlane((int)dhi, k1)) << 32)
                   |  ((u64)(u32)__builtin_amdgcn_readlane((int)dlo, k1));
            u64 c1 = cand & ~(1ull << k1);
            kw |= 1ull << k1;
            if (c1) {   // speculative second candidate (suppression is sparse)
                int k2 = __builtin_amdgcn_readfirstlane((int)__builtin_ctzll(c1));
                u64 s2 = (((u64)(u32)__builtin_amdgcn_readlane((int)dhi, k2)) << 32)
                       |  ((u64)(u32)__builtin_amdgcn_readlane((int)dlo, k2));
                if (!((s1 >> k2) & 1ull)) {
                    kw |= 1ull << k2;
                    cand = c1 & ~(1ull << k2) & ~(s1 | s2);
                } else {
                    cand = c1 & ~s1;
                }
            } else cand = 0;
        }
        if (t == 0 && p < nw) s_kws[p] = kw;
        // ---- near update: word p+1 from band regs (d=1) ----
        u64 mm = ((kw >> t) & 1ull) ? ~0ull : 0ull;
        u64 r1 = BU.y & mm;
        #pragma unroll
        for (int m = 1; m < 64; m <<= 1) r1 |= shfl_xor_u64(r1, m);
        if (t == 0 && p + 1 < nw && r1)
            atomicOr((unsigned long long*)&s_remv[p + 1], (unsigned long long)r1);
        // ---- issue db2 regs for chunk p+2 (coalesced 16B/lane) ----
        BI = db2v[(size_t)min(p + 2, nw - 1) * 64 + t];
    } else {
        // ---- APPLY chunk q = p-1 edge-words (issued 2 phases ago) ----
        int q = p - 1;
        u64 kwq = (q >= 0 && q < nw) ? s_kws[q] : 0ull;
        #pragma unroll
        for (int j = 0; j < EPF; ++j) {
            if (EI[j] != 0xFFFFFFFFu) {
                int row = (int)(EI[j] >> 8);
                if ((kwq >> row) & 1ull)
                    atomicOr((unsigned long long*)&s_remv[EI[j] & 255u],
                             (unsigned long long)EM[j]);
            }
        }
        if (q >= 0 && q < nw) {          // never-triggered overflow guard
            int cq = s_cnt[q];
            for (int s = 448 * EPF + tf; s < cq; s += 448) {
                u32 ei = einfo[(size_t)q * EC + s];
                u64 em = emask[(size_t)q * EC + s];
                if ((kwq >> (ei >> 8)) & 1ull)
                    atomicOr((unsigned long long*)&s_remv[ei & 255u],
                             (unsigned long long)em);
            }
        }
        // ---- ISSUE chunk p+1 edge-words (static addresses, no wait) ----
        int ip = p + 1;
        int cn = (ip < nw) ? s_cnt[ip] : 0;
        #pragma unroll
        for (int j = 0; j < EPF; ++j) {
            int s = tf + j * 448;
            EI[j] = 0xFFFFFFFFu;
            if (s < cn) {
                EI[j] = einfo[(size_t)ip * EC + s];
                EM[j] = emask[(size_t)ip * EC + s];
            }
        }
    }
    lgkm_barrier();
}

__global__ __launch_bounds__(512) void nms_scan(const u64* __restrict__ db2,
                                                const u32* __restrict__ einfo,
                                                const u64* __restrict__ emask,
                                                const int* __restrict__ ecnt,
                                                const float* __restrict__ sbox,
                                                const float* __restrict__ sconf,
                                                int n, int nw,
                                                float* __restrict__ out) {
    __shared__ u64 s_remv[MAXNW];
    __shared__ u64 s_kws[MAXNW];
    __shared__ int s_cnt[MAXNW];

    int t  = threadIdx.x;
    int tf = t - 64;
    const ulonglong2* db2v = (const ulonglong2*)db2;

    for (int i = t; i < MAXNW; i += 512) {
        s_remv[i] = 0; s_kws[i] = 0;
        s_cnt[i] = (i < nw) ? min(ecnt[i], EC) : 0;
    }
    __syncthreads();

    ulonglong2 B0, B1, B2;
    u32 EIa[EPF], EIb[EPF];
    u64 EMa[EPF], EMb[EPF];
    #pragma unroll
    for (int j = 0; j < EPF; ++j) { EIa[j] = 0xFFFFFFFFu; EIb[j] = 0xFFFFFFFFu; EMa[j] = 0; EMb[j] = 0; }

    if (t < 64) {   // prologue: db2 for chunks 0,1
        B0 = db2v[t];
        B1 = db2v[64 + t];
        B2 = make_ulonglong2(0, 0);
    } else {        // prologue: edges of chunk 0 into odd buffer (applied phase 1)
        int cn = s_cnt[0];
        #pragma unroll
        for (int j = 0; j < EPF; ++j) {
            int s = tf + j * 448;
            if (s < cn) { EIb[j] = einfo[s]; EMb[j] = emask[s]; }
        }
    }
    __syncthreads();

    int NPH = ((nw + 5) / 6) * 6;     // padded tail phases are no-ops
    for (int pb = 0; pb < NPH; pb += 6) {
        phase_step<0>(pb+0, n, nw, t, tf, db2v, einfo, emask, s_remv, s_kws, s_cnt, B0, B2, EIa, EMa);
        phase_step<1>(pb+1, n, nw, t, tf, db2v, einfo, emask, s_remv, s_kws, s_cnt, B1, B0, EIb, EMb);
        phase_step<0>(pb+2, n, nw, t, tf, db2v, einfo, emask, s_remv, s_kws, s_cnt, B2, B1, EIa, EMa);
        phase_step<1>(pb+3, n, nw, t, tf, db2v, einfo, emask, s_remv, s_kws, s_cnt, B0, B2, EIb, EMb);
        phase_step<0>(pb+4, n, nw, t, tf, db2v, einfo, emask, s_remv, s_kws, s_cnt, B1, B0, EIa, EMa);
        phase_step<1>(pb+5, n, nw, t, tf, db2v, einfo, emask, s_remv, s_kws, s_cnt, B2, B1, EIb, EMb);
    }
    __syncthreads();

    // ---- masked output ----
    for (int e = t; e < n * 5; e += 512) {
        int r = e / 5, c5 = e - r * 5;
        float keep = ((s_kws[r >> 6] >> (r & 63)) & 1ull) ? 1.0f : 0.0f;
        float v = (c5 < 4) ? sbox[(size_t)r * 4 + c5] : sconf[r];
        out[e] = v * keep;
    }
}

// ---------------- launch -----------------------------------------------------
extern "C" void kernel_launch(void* const* d_in, const int* in_sizes, int n_in,
                              void* d_out, int out_size, void* d_ws, size_t ws_size,
                              hipStream_t stream) {
    const float* yb = (const float*)d_in[0];
    const float* yc = (const float*)d_in[1];
    const float* db = (const float*)d_in[2];
    const float* dc = (const float*)d_in[3];
    int n1 = in_sizes[1];
    int n2 = in_sizes[3];
    int n  = n1 + n2;                          // 8700
    int nw = (n + 63) / 64;                    // 136

    char* w = (char*)d_ws;
    u64*    emask = (u64*)w;                                   // MAXNW*EC u64 = 4.72 MB
    u64*    db2   = emask + (size_t)MAXNW * EC;                // 2*MAXN u64
    float4* xyxy  = (float4*)(db2 + (size_t)2 * MAXN);
    float4* sbox  = xyxy + MAXN;
    float*  conf  = (float*)(sbox + MAXN);
    float*  sconf = conf + MAXN;
    u32*    key   = (u32*)(sconf + MAXN);
    int*    rank  = (int*)(key + MAXN);
    int*    ecnt  = rank + MAXN;                               // MAXNW ints
    u32*    einfo = (u32*)(ecnt + MAXNW);                      // MAXNW*EC u32 = 2.36 MB

    int nb = (n + 255) / 256;                                  // 34
    prep_kernel<<<nb, 256, 0, stream>>>(yb, yc, db, dc, n1, n, xyxy, conf, key, rank,
                                        db2, ecnt);

    dim3 g1(nb, (n + CHUNK - 1) / CHUNK);                      // 34 x 17
    rank_kernel<<<g1, 256, 0, stream>>>(key, n, rank);

    scatter_kernel<<<nb, 256, 0, stream>>>(xyxy, conf, rank, n, sbox, sconf);

    dim3 g3(nw, nw);                                           // 136 x 136 (upper tri active)
    iou_kernel<<<g3, 64, 0, stream>>>(sbox, n, nw, db2, einfo, emask, ecnt);

    nms_scan<<<1, 512, 0, stream>>>(db2, einfo, emask, ecnt, (const float*)sbox, sconf,
                                    n, nw, (float*)d_out);
}

// Round 8
// 456.939 us; speedup vs baseline: 1.3201x; 1.2940x over previous
//
#include <hip/hip_runtime.h>

typedef unsigned long long u64;
typedef unsigned int u32;

#define MAXN 8704            // 8700 rounded to 64
#define MAXNW 144
#define CHUNK 512            // j-chunk for rank kernel
#define EC 4096              // edge-word slots per source chunk (~50x headroom)
#define EPW 8                // edge regs/lane: 64*8 = 512 slots fast path

// ---------------- K0: merge + clip + cxcywh->xyxy + sort key + ws init ------
__global__ void prep_kernel(const float* __restrict__ yb, const float* __restrict__ yc,
                            const float* __restrict__ db, const float* __restrict__ dc,
                            int n1, int n,
                            float4* __restrict__ xyxy, float* __restrict__ conf,
                            u32* __restrict__ key, int* __restrict__ rank,
                            u64* __restrict__ diag_g, u64* __restrict__ tb1,
                            int* __restrict__ ecnt) {
    int i = blockIdx.x * 256 + threadIdx.x;
    if (i < MAXN) { rank[i] = 0; diag_g[i] = 0; tb1[i] = 0; }
    if (i < MAXNW) ecnt[i] = 0;
    if (i >= n) return;
    float cx, cy, w, h, c;
    if (i < n1) {
        const float* b = yb + (size_t)i * 4;
        cx = b[0]; cy = b[1]; w = b[2]; h = b[3]; c = yc[i];
    } else {
        const float* b = db + (size_t)(i - n1) * 4;
        cx = b[0]; cy = b[1]; w = b[2]; h = b[3]; c = dc[i - n1];
    }
    c = fminf(fmaxf(c, 0.0f), 1.0f);
    float hw = w * 0.5f, hh = h * 0.5f;
    xyxy[i] = make_float4(cx - hw, cy - hh, cx + hw, cy + hh);
    conf[i] = c;
    key[i]  = __float_as_uint(c);
}

// ---------------- K1: O(N^2) stable rank ------------------------------------
__global__ void rank_kernel(const u32* __restrict__ key, int n, int* __restrict__ rank) {
    __shared__ __align__(16) u32 sk[CHUNK];
    int t = threadIdx.x;
    int jbase = blockIdx.y * CHUNK;
    for (int s = t; s < CHUNK; s += 256) {
        int j = jbase + s;
        sk[s] = (j < n) ? key[j] : 0u;
    }
    __syncthreads();
    int i = blockIdx.x * 256 + t;
    if (i >= n) return;
    u32 ki = key[i];
    int cnt = 0;
    const uint4* sk4 = (const uint4*)sk;
    for (int s = 0; s < CHUNK / 4; ++s) {
        uint4 k = sk4[s];
        int j = jbase + s * 4;
        cnt += (k.x > ki) || (k.x == ki && (j + 0) < i);
        cnt += (k.y > ki) || (k.y == ki && (j + 1) < i);
        cnt += (k.z > ki) || (k.z == ki && (j + 2) < i);
        cnt += (k.w > ki) || (k.w == ki && (j + 3) < i);
    }
    if (cnt) atomicAdd(&rank[i], cnt);
}

// ---------------- K2: scatter into sorted order -----------------------------
__global__ void scatter_kernel(const float4* __restrict__ xyxy, const float* __restrict__ conf,
                               const int* __restrict__ rank, int n,
                               float4* __restrict__ sbox, float* __restrict__ sconf) {
    int i = blockIdx.x * 256 + threadIdx.x;
    if (i >= n) return;
    int r = rank[i];
    sbox[r]  = xyxy[i];
    sconf[r] = conf[i];
}

// ---------------- K3: SPARSE suppression structure ---------------------------
// d=0 -> diag_g[i] (diagonal 64x64 block, row-major).
// d=1 -> tb1[j] TRANSPOSED: bit r set <=> source row r (chunk bi) suppresses
//        target row j (chunk bi+1). Enables ballot-based near-update.
// d>=2 & word!=0 -> edge-word {einfo=(row<<8)|bj, emask=word} bucketed by bi.
__global__ void iou_kernel(const float4* __restrict__ sbox, int n, int nw,
                           u64* __restrict__ diag_g, u64* __restrict__ tb1,
                           u32* __restrict__ einfo, u64* __restrict__ emask,
                           int* __restrict__ ecnt) {
    int bi = blockIdx.y, bj = blockIdx.x;
    if (bj < bi) return;
    __shared__ float4 cb[64];
    __shared__ float4 cb2[64];
    int t  = threadIdx.x;
    int j0 = bj * 64;
    int jt = j0 + t;
    int d  = bj - bi;
    float4 myj = (jt < n) ? sbox[jt] : make_float4(0, 0, 0, 0);
    cb[t] = myj;
    if (d == 1) cb2[t] = (bi * 64 + t < n) ? sbox[bi * 64 + t] : make_float4(0, 0, 0, 0);
    __syncthreads();

    if (d == 1) {
        // transposed band: my column box vs all source rows of chunk bi
        float areaT = (myj.z - myj.x) * (myj.w - myj.y);
        u64 w2 = 0;
        for (int k = 0; k < 64; ++k) {
            float4 b = cb2[k];
            float iw = fmaxf(fminf(b.z, myj.z) - fmaxf(b.x, myj.x), 0.0f);
            float ih = fmaxf(fminf(b.w, myj.w) - fmaxf(b.y, myj.y), 0.0f);
            float inter = iw * ih;
            float areaB = (b.z - b.x) * (b.w - b.y);
            float uni = areaB + areaT - inter;
            float iou = inter / fmaxf(uni, 1e-9f);
            if (iou > 0.5f) w2 |= (1ULL << k);
        }
        tb1[(size_t)j0 + t] = w2;   // zero-boxes give iou=0 -> safe
        return;
    }

    int i = bi * 64 + t;
    if (i >= n) return;
    float4 a = sbox[i];
    float areaA = (a.z - a.x) * (a.w - a.y);
    u64 word = 0;
    int kmax = min(64, n - j0);
    for (int k = 0; k < kmax; ++k) {
        int j = j0 + k;
        float4 b = cb[k];
        float iw = fmaxf(fminf(a.z, b.z) - fmaxf(a.x, b.x), 0.0f);
        float ih = fmaxf(fminf(a.w, b.w) - fmaxf(a.y, b.y), 0.0f);
        float inter = iw * ih;
        float areaB = (b.z - b.x) * (b.w - b.y);
        float uni = areaA + areaB - inter;
        float iou = inter / fmaxf(uni, 1e-9f);
        if (j > i && iou > 0.5f) word |= (1ULL << k);
    }
    if (d == 0) diag_g[i] = word;
    else if (word) {
        int slot = atomicAdd(&ecnt[bi], 1);
        if (slot < EC) {
            einfo[(size_t)bi * EC + slot] = ((u32)t << 8) | (u32)bj;
            emask[(size_t)bi * EC + slot] = word;
        }
    }
}

// ---------------- K4: SINGLE-WAVE sparse forward-substitution NMS -----------
// Wave 0 alone runs the whole chain -- zero barriers, zero cross-wave traffic.
// Per chunk p: ctz-solve diag (regs, prefetched 2 ahead) using register-
// carried CUR; near word p+1 via ballot over transposed band regs (replaces
// the 6-level shfl tree); apply chunk p's edge-words (LDS atomicOr, targets
// >= p+2); CUR_next = s_remv[p+1] (read early, all writers finished) | r1;
// prefetch diag/tb/edges for later chunks. Compiler schedules freely -- no
// sched_barrier/waitcnt pins. Waves 1-7 sleep at the final __syncthreads,
// then all 512 threads write the masked output.
// Coverage of word w: diag (chunk w) + band1 (ballot at w-1) + edges from
// chunks q<=w-2 (applied at their own phase q <= w-2). Exact greedy NMS.
static __device__ __forceinline__ void phase1(
    int p, int n, int nw, int t,
    const u64* __restrict__ diag_g, const u64* __restrict__ tb1,
    const u32* __restrict__ einfo, const u64* __restrict__ emask,
    u64* s_remv, u64* s_kws, const int* s_cnt,
    u64& CUR, u64 BU, u64 TBc, u64& BI, u64& TBi,
    u32 (&EIc)[EPW], u64 (&EMc)[EPW], u32 (&EIi)[EPW], u64 (&EMi)[EPW])
{
    // ---- solve chunk p (ctz-skip chain, diag slices in lane regs) ----
    int rem = n - (p << 6);
    u64 vm = (rem >= 64) ? ~0ull : (rem <= 0 ? 0ull : ((1ull << rem) - 1ull));
    u64 cand = ~CUR & vm;
    u64 kw = 0;
    u32 dlo = (u32)BU, dhi = (u32)(BU >> 32);
    while (cand) {
        int k1 = __builtin_amdgcn_readfirstlane((int)__builtin_ctzll(cand));
        u64 s1 = (((u64)(u32)__builtin_amdgcn_readlane((int)dhi, k1)) << 32)
               |  ((u64)(u32)__builtin_amdgcn_readlane((int)dlo, k1));
        u64 c1 = cand & ~(1ull << k1);
        kw |= 1ull << k1;
        if (c1) {   // speculative second candidate (suppression is sparse)
            int k2 = __builtin_amdgcn_readfirstlane((int)__builtin_ctzll(c1));
            u64 s2 = (((u64)(u32)__builtin_amdgcn_readlane((int)dhi, k2)) << 32)
                   |  ((u64)(u32)__builtin_amdgcn_readlane((int)dlo, k2));
            if (!((s1 >> k2) & 1ull)) {
                kw |= 1ull << k2;
                cand = c1 & ~(1ull << k2) & ~(s1 | s2);
            } else {
                cand = c1 & ~s1;
            }
        } else cand = 0;
    }
    if (t == 0 && p < nw) s_kws[p] = kw;
    // ---- next-word read: all writers (chunks <= p-1) already ran; this
    //      phase's edge applies target >= p+2, never p+1 -> safe & early ----
    u64 nxt = s_remv[min(p + 1, MAXNW - 1)];
    // ---- near update via ballot over transposed band ----
    u64 r1 = __ballot((TBc & kw) != 0ull);
    // ---- apply chunk p's edge-words (gated by kw; targets >= p+2) ----
    #pragma unroll
    for (int j = 0; j < EPW; ++j) {
        if (EIc[j] != 0xFFFFFFFFu && ((kw >> (EIc[j] >> 8)) & 1ull))
            atomicOr((unsigned long long*)&s_remv[EIc[j] & 255u],
                     (unsigned long long)EMc[j]);
    }
    if (p < nw) {                     // rare overflow path (>512 edge-words)
        int cq = s_cnt[p];
        for (int s = 64 * EPW + t; s < cq; s += 64) {
            u32 ei = einfo[(size_t)p * EC + s];
            u64 em = emask[(size_t)p * EC + s];
            if ((kw >> (ei >> 8)) & 1ull)
                atomicOr((unsigned long long*)&s_remv[ei & 255u],
                         (unsigned long long)em);
        }
    }
    CUR = nxt | r1;
    // ---- feed-forward prefetches (off the dependency chain) ----
    BI  = diag_g[(size_t)min(p + 2, nw - 1) * 64 + t];
    TBi = tb1[(size_t)min(p + 3, nw - 1) * 64 + t];
    int ip = p + 1;
    int cn = (ip < nw) ? s_cnt[ip] : 0;
    #pragma unroll
    for (int j = 0; j < EPW; ++j) {
        int s = t + j * 64;
        EIi[j] = 0xFFFFFFFFu;
        if (s < cn) {
            EIi[j] = einfo[(size_t)ip * EC + s];
            EMi[j] = emask[(size_t)ip * EC + s];
        }
    }
}

__global__ __launch_bounds__(512) void nms_scan(const u64* __restrict__ diag_g,
                                                const u64* __restrict__ tb1,
                                                const u32* __restrict__ einfo,
                                                const u64* __restrict__ emask,
                                                const int* __restrict__ ecnt,
                                                const float* __restrict__ sbox,
                                                const float* __restrict__ sconf,
                                                int n, int nw,
                                                float* __restrict__ out) {
    __shared__ u64 s_remv[MAXNW];
    __shared__ u64 s_kws[MAXNW];
    __shared__ int s_cnt[MAXNW];

    int t = threadIdx.x;

    if (t < 64) {
        for (int i = t; i < MAXNW; i += 64) {
            s_remv[i] = 0; s_kws[i] = 0;
            s_cnt[i] = (i < nw) ? min(ecnt[i], EC) : 0;
        }
        u64 B0 = diag_g[t], B1 = diag_g[64 + t], B2 = 0;
        u64 T0 = tb1[(size_t)min(1, nw - 1) * 64 + t];
        u64 T1 = tb1[(size_t)min(2, nw - 1) * 64 + t];
        u64 T2 = 0;
        u32 EIa[EPW], EIb[EPW];
        u64 EMa[EPW], EMb[EPW];
        #pragma unroll
        for (int j = 0; j < EPW; ++j) { EIa[j] = 0xFFFFFFFFu; EIb[j] = 0xFFFFFFFFu; EMa[j] = 0; EMb[j] = 0; }
        {   // prologue: edges of chunk 0 (same-wave LDS write->read is ordered)
            int cn = s_cnt[0];
            #pragma unroll
            for (int j = 0; j < EPW; ++j) {
                int s = t + j * 64;
                if (s < cn) { EIa[j] = einfo[s]; EMa[j] = emask[s]; }
            }
        }
        u64 CUR = 0;

        int NPH = ((nw + 5) / 6) * 6;     // padded tail chunks are no-ops
        for (int pb = 0; pb < NPH; pb += 6) {
            phase1(pb+0, n, nw, t, diag_g, tb1, einfo, emask, s_remv, s_kws, s_cnt,
                   CUR, B0, T0, B2, T2, EIa, EMa, EIb, EMb);
            phase1(pb+1, n, nw, t, diag_g, tb1, einfo, emask, s_remv, s_kws, s_cnt,
                   CUR, B1, T1, B0, T0, EIb, EMb, EIa, EMa);
            phase1(pb+2, n, nw, t, diag_g, tb1, einfo, emask, s_remv, s_kws, s_cnt,
                   CUR, B2, T2, B1, T1, EIa, EMa, EIb, EMb);
            phase1(pb+3, n, nw, t, diag_g, tb1, einfo, emask, s_remv, s_kws, s_cnt,
                   CUR, B0, T0, B2, T2, EIb, EMb, EIa, EMa);
            phase1(pb+4, n, nw, t, diag_g, tb1, einfo, emask, s_remv, s_kws, s_cnt,
                   CUR, B1, T1, B0, T0, EIa, EMa, EIb, EMb);
            phase1(pb+5, n, nw, t, diag_g, tb1, einfo, emask, s_remv, s_kws, s_cnt,
                   CUR, B2, T2, B1, T1, EIb, EMb, EIa, EMa);
        }
    }
    __syncthreads();   // waves 1-7 slept here; s_kws now visible to all

    // ---- masked output (all 512 threads) ----
    for (int e = t; e < n * 5; e += 512) {
        int r = e / 5, c5 = e - r * 5;
        float keep = ((s_kws[r >> 6] >> (r & 63)) & 1ull) ? 1.0f : 0.0f;
        float v = (c5 < 4) ? sbox[(size_t)r * 4 + c5] : sconf[r];
        out[e] = v * keep;
    }
}

// ---------------- launch -----------------------------------------------------
extern "C" void kernel_launch(void* const* d_in, const int* in_sizes, int n_in,
                              void* d_out, int out_size, void* d_ws, size_t ws_size,
                              hipStream_t stream) {
    const float* yb = (const float*)d_in[0];
    const float* yc = (const float*)d_in[1];
    const float* db = (const float*)d_in[2];
    const float* dc = (const float*)d_in[3];
    int n1 = in_sizes[1];
    int n2 = in_sizes[3];
    int n  = n1 + n2;                          // 8700
    int nw = (n + 63) / 64;                    // 136

    char* w = (char*)d_ws;
    u64*    diag_g = (u64*)w;                                  // MAXN u64
    u64*    tb1    = diag_g + MAXN;                            // MAXN u64
    u64*    emask  = tb1 + MAXN;                               // MAXNW*EC u64
    u32*    einfo  = (u32*)(emask + (size_t)MAXNW * EC);       // MAXNW*EC u32
    int*    ecnt   = (int*)(einfo + (size_t)MAXNW * EC);       // MAXNW ints
    float4* xyxy   = (float4*)(ecnt + MAXNW);
    float4* sbox   = xyxy + MAXN;
    float*  conf   = (float*)(sbox + MAXN);
    float*  sconf  = conf + MAXN;
    u32*    key    = (u32*)(sconf + MAXN);
    int*    rank   = (int*)(key + MAXN);

    int nb = (n + 255) / 256;                                  // 34
    prep_kernel<<<nb, 256, 0, stream>>>(yb, yc, db, dc, n1, n, xyxy, conf, key, rank,
                                        diag_g, tb1, ecnt);

    dim3 g1(nb, (n + CHUNK - 1) / CHUNK);                      // 34 x 17
    rank_kernel<<<g1, 256, 0, stream>>>(key, n, rank);

    scatter_kernel<<<nb, 256, 0, stream>>>(xyxy, conf, rank, n, sbox, sconf);

    dim3 g3(nw, nw);                                           // 136 x 136 (upper tri active)
    iou_kernel<<<g3, 64, 0, stream>>>(sbox, n, nw, diag_g, tb1, einfo, emask, ecnt);

    nms_scan<<<1, 512, 0, stream>>>(diag_g, tb1, einfo, emask, ecnt,
                                    (const float*)sbox, sconf, n, nw, (float*)d_out);
}